// Round 5
// baseline (547.945 us; speedup 1.0000x reference)
//
#include <hip/hip_runtime.h>

// ChebTimeConv: N=50000, E=1.6M, H=4, F_IN=F_OUT=32, K=4, Q=1.
// count/fill: XCD-range-split + NONTEMPORAL edge-stream loads (keep csr
// window L2-resident so partial-line writes coalesce). CSR entry packed 4B:
// (col<<16)|bf16(lap). SpMM: one wave/node, unroll-8 gather (MLP), bf16
// mirrors, fused einsum epilogue with bank-conflict-free padded LDS.

#define FEAT 128   // H * F_IN
#define GOUT 32    // F_OUT
#define SCB 256
#define WPB 8
#define FILLCH 4096
#define TROW 160   // padded LDS row: +4 floats per 16

typedef unsigned int uint;
typedef unsigned short ushort;

__device__ __forceinline__ ushort f2bf(float f) {
    uint u = __float_as_uint(f);
    return (ushort)((u + 0x7fffu + ((u >> 16) & 1u)) >> 16);   // RNE
}
__device__ __forceinline__ float bflo(uint u) { return __uint_as_float(u << 16); }
__device__ __forceinline__ float bfhi(uint u) { return __uint_as_float(u & 0xffff0000u); }
__device__ __forceinline__ int tidx(int i) { return i + ((i >> 4) << 2); }

// ---- degree count: row-range split (XCD-local atomics), NT streams ----
__global__ void count_kernel(const int* __restrict__ ei, int E, int* __restrict__ cnt,
                             int rchunk) {
    int rlo = (blockIdx.x & 7) * rchunk, rhi = rlo + rchunk;
    int e0 = (blockIdx.x >> 3) * FILLCH;
    int e1 = min(e0 + FILLCH, E);
    for (int e = e0 + (int)threadIdx.x; e < e1; e += 256) {
        int r = __builtin_nontemporal_load(ei + e);
        if (r < rlo || r >= rhi) continue;
        int c = __builtin_nontemporal_load(ei + (size_t)E + e);
        if (r != c) atomicAdd(&cnt[r], 1);
    }
}

// ---- two-level scan (dinv folded into scan1) ----
__global__ void scan1_kernel(const int* __restrict__ cnt, int* __restrict__ partial,
                             int* __restrict__ blockSums, float* __restrict__ dinv, int n) {
    __shared__ int buf[2][SCB];
    int t = threadIdx.x;
    int i = blockIdx.x * SCB + t;
    int v = (i < n) ? cnt[i] : 0;
    if (i < n) dinv[i] = (v > 0) ? rsqrtf((float)v) : 0.0f;
    buf[0][t] = v;
    __syncthreads();
    int src = 0;
    for (int off = 1; off < SCB; off <<= 1) {
        int d = src ^ 1;
        buf[d][t] = buf[src][t] + ((t >= off) ? buf[src][t - off] : 0);
        __syncthreads();
        src = d;
    }
    int incl = buf[src][t];
    if (i < n) partial[i] = incl - v;
    if (t == SCB - 1) blockSums[blockIdx.x] = incl;
}

__global__ void scan2_kernel(const int* __restrict__ blockSums, int* __restrict__ blockOffsets,
                             int nb, int* __restrict__ total_out) {
    __shared__ int buf[2][SCB];
    __shared__ int carry_s;
    if (threadIdx.x == 0) carry_s = 0;
    __syncthreads();
    for (int base = 0; base < nb; base += SCB) {
        int i = base + (int)threadIdx.x;
        int v = (i < nb) ? blockSums[i] : 0;
        buf[0][threadIdx.x] = v;
        __syncthreads();
        int src = 0;
        for (int off = 1; off < SCB; off <<= 1) {
            int d = src ^ 1;
            buf[d][threadIdx.x] = buf[src][threadIdx.x] +
                                  ((threadIdx.x >= (unsigned)off) ? buf[src][threadIdx.x - off] : 0);
            __syncthreads();
            src = d;
        }
        int incl = buf[src][threadIdx.x];
        int c = carry_s;
        if (i < nb) blockOffsets[i] = c + incl - v;
        __syncthreads();
        if (threadIdx.x == SCB - 1) carry_s = c + incl;
        __syncthreads();
    }
    if (threadIdx.x == 0) *total_out = carry_s;
}

__global__ void scan3_kernel(const int* __restrict__ partial, const int* __restrict__ blockOffsets,
                             int* __restrict__ offsets, int n) {
    int i = blockIdx.x * blockDim.x + threadIdx.x;
    if (i < n) offsets[i] = partial[i] + blockOffsets[i / SCB];
}

// ---- CSR fill: row-range split, NT edge-stream loads ----
__global__ void fill_kernel(const int* __restrict__ ei, const float* __restrict__ ew,
                            const int* __restrict__ offsets, int* __restrict__ cursor,
                            const float* __restrict__ dinv, uint* __restrict__ csr,
                            int E, int rchunk) {
    int rlo = (blockIdx.x & 7) * rchunk, rhi = rlo + rchunk;
    int e0 = (blockIdx.x >> 3) * FILLCH;
    int e1 = min(e0 + FILLCH, E);
    for (int e = e0 + (int)threadIdx.x; e < e1; e += 256) {
        int r = __builtin_nontemporal_load(ei + e);
        if (r < rlo || r >= rhi) continue;
        int c = __builtin_nontemporal_load(ei + (size_t)E + e);
        if (r == c) continue;                        // self loop: lap == 0, drop
        float w = __builtin_nontemporal_load(ew + e);
        int pos = offsets[r] + atomicAdd(&cursor[r], 1);
        float lap = -dinv[r] * w * dinv[c];
        csr[pos] = ((uint)c << 16) | (uint)f2bf(lap);
    }
}

// ---- fused: x -> bf16 mirror, plus out = bias + x*W0 ----
// block 256 = 8 nodes; 32 threads/node (q = g-quad, part = i-range of 32).
__global__ __launch_bounds__(256) void cvt_einsum0_kernel(
    const float* __restrict__ x, ushort* __restrict__ xb,
    const float* __restrict__ W0, const float* __restrict__ bias,
    float* __restrict__ out, int n) {
    __shared__ __align__(16) float4 sW4[FEAT * GOUT / 4];
    __shared__ __align__(16) float sT[8 * TROW];
    const float* sW = (const float*)sW4;
    int t = threadIdx.x;
    const float4* wsrc = (const float4*)W0;
    for (int idx = t; idx < FEAT * GOUT / 4; idx += 256) sW4[idx] = wsrc[idx];
    size_t gi = (size_t)blockIdx.x * (8 * FEAT) + (size_t)t * 4;
    float4 v = make_float4(0.f, 0.f, 0.f, 0.f);
    bool inb = gi < (size_t)n * FEAT;
    if (inb) {
        v = *(const float4*)(x + gi);
        ushort4 o;
        o.x = f2bf(v.x); o.y = f2bf(v.y); o.z = f2bf(v.z); o.w = f2bf(v.w);
        *(ushort4*)(xb + gi) = o;
    }
    int nl = t >> 5;
    int f0 = 4 * (t & 31);
    *(float4*)&sT[nl * TROW + tidx(f0)] = v;
    __syncthreads();
    int l32 = t & 31;
    int q = l32 & 7;            // g = 4q..4q+3
    int part = l32 >> 3;        // i in [part*32, part*32+32)
    float4 a4 = make_float4(0.f, 0.f, 0.f, 0.f);
#pragma unroll
    for (int j = 0; j < 8; ++j) {
        float4 t4 = *(const float4*)&sT[nl * TROW + tidx(part * 32 + 4 * j)];
        const float* wv0 = &sW[(part * 32 + 4 * j) * GOUT + 4 * q];
        float4 w0 = *(const float4*)(wv0);
        float4 w1 = *(const float4*)(wv0 + GOUT);
        float4 w2 = *(const float4*)(wv0 + 2 * GOUT);
        float4 w3 = *(const float4*)(wv0 + 3 * GOUT);
        a4.x += t4.x * w0.x + t4.y * w1.x + t4.z * w2.x + t4.w * w3.x;
        a4.y += t4.x * w0.y + t4.y * w1.y + t4.z * w2.y + t4.w * w3.y;
        a4.z += t4.x * w0.z + t4.y * w1.z + t4.z * w2.z + t4.w * w3.z;
        a4.w += t4.x * w0.w + t4.y * w1.w + t4.z * w2.w + t4.w * w3.w;
    }
    a4.x += __shfl_down(a4.x, 8);  a4.y += __shfl_down(a4.y, 8);
    a4.z += __shfl_down(a4.z, 8);  a4.w += __shfl_down(a4.w, 8);
    a4.x += __shfl_down(a4.x, 16); a4.y += __shfl_down(a4.y, 16);
    a4.z += __shfl_down(a4.z, 16); a4.w += __shfl_down(a4.w, 16);
    int node = blockIdx.x * 8 + nl;
    if (part == 0 && node < n) {
        const float4 b4 = *(const float4*)(bias + 4 * q);
        float4 r;
        r.x = a4.x + b4.x; r.y = a4.y + b4.y; r.z = a4.z + b4.z; r.w = a4.w + b4.w;
        *(float4*)(out + (size_t)node * GOUT + 4 * q) = r;
    }
}

// ---- SpMM (one wave per node, unroll-8 gather) + fused einsum epilogue ----
__global__ __launch_bounds__(512) void spmm_fused_kernel(
    const ushort* __restrict__ inb, const ushort* __restrict__ sub,
    ushort* __restrict__ outb, const int* __restrict__ offsets,
    const uint* __restrict__ csr, const float* __restrict__ Wk,
    float* __restrict__ out, int n, int has_sub) {
    __shared__ __align__(16) float4 sW4[FEAT * GOUT / 4];   // 16 KB
    __shared__ __align__(16) float sT[WPB][TROW];           // 5 KB (padded)
    const float* sW = (const float*)sW4;
    int w = threadIdx.x >> 6;
    int lane = threadIdx.x & 63;
    int node = blockIdx.x * WPB + w;
    const float4* wsrc = (const float4*)Wk;
    for (int idx = threadIdx.x; idx < FEAT * GOUT / 4; idx += 512) sW4[idx] = wsrc[idx];
    float ox = 0.f, oy = 0.f;
    if (node < n) {
        int beg = offsets[node], end = offsets[node + 1];
        float ax = 0.f, ay = 0.f;
        int j = beg;
        for (; j + 8 <= end; j += 8) {
            uint q[8], u[8];
#pragma unroll
            for (int k = 0; k < 8; ++k) q[k] = __builtin_nontemporal_load(csr + j + k);
#pragma unroll
            for (int k = 0; k < 8; ++k)
                u[k] = ((const uint*)(inb + (size_t)(q[k] >> 16) * FEAT))[lane];
#pragma unroll
            for (int k = 0; k < 8; ++k) {
                float l = bflo(q[k]);
                ax += l * bflo(u[k]);
                ay += l * bfhi(u[k]);
            }
        }
        for (; j < end; ++j) {
            uint qe = __builtin_nontemporal_load(csr + j);
            uint u = ((const uint*)(inb + (size_t)(qe >> 16) * FEAT))[lane];
            float l = bflo(qe);
            ax += l * bflo(u);
            ay += l * bfhi(u);
        }
        ox = ax; oy = ay;
        if (has_sub) {
            uint s = __builtin_nontemporal_load((const uint*)(sub + (size_t)node * FEAT) + lane);
            ox = 2.f * ax - bflo(s);
            oy = 2.f * ay - bfhi(s);
        }
        uint o = (uint)f2bf(ox) | ((uint)f2bf(oy) << 16);
        __builtin_nontemporal_store(o, (uint*)(outb + (size_t)node * FEAT) + lane);
    }
    *(float2*)&sT[w][tidx(2 * lane)] = make_float2(ox, oy);
    __syncthreads();
    // epilogue: out[node, 4q..4q+3] += sum_i T[i] * Wk[i, 4q..4q+3]
    int q = lane & 7;           // g quad
    int part = lane >> 3;       // i in [16*part, 16*part+16)
    float4 a4 = make_float4(0.f, 0.f, 0.f, 0.f);
#pragma unroll
    for (int j = 0; j < 4; ++j) {
        float4 t4 = *(const float4*)&sT[w][20 * part + 4 * j];   // tidx(16p+4j)
        const float* wv0 = &sW[(part * 16 + 4 * j) * GOUT + 4 * q];
        float4 w0 = *(const float4*)(wv0);
        float4 w1 = *(const float4*)(wv0 + GOUT);
        float4 w2 = *(const float4*)(wv0 + 2 * GOUT);
        float4 w3 = *(const float4*)(wv0 + 3 * GOUT);
        a4.x += t4.x * w0.x + t4.y * w1.x + t4.z * w2.x + t4.w * w3.x;
        a4.y += t4.x * w0.y + t4.y * w1.y + t4.z * w2.y + t4.w * w3.y;
        a4.z += t4.x * w0.z + t4.y * w1.z + t4.z * w2.z + t4.w * w3.z;
        a4.w += t4.x * w0.w + t4.y * w1.w + t4.z * w2.w + t4.w * w3.w;
    }
#pragma unroll
    for (int off = 8; off < 64; off <<= 1) {
        a4.x += __shfl_down(a4.x, off);
        a4.y += __shfl_down(a4.y, off);
        a4.z += __shfl_down(a4.z, off);
        a4.w += __shfl_down(a4.w, off);
    }
    if (part == 0 && node < n) {
        float4* po = (float4*)(out + (size_t)node * GOUT + 4 * q);
        float4 cur = *po;
        cur.x += a4.x; cur.y += a4.y; cur.z += a4.z; cur.w += a4.w;
        *po = cur;
    }
}

extern "C" void kernel_launch(void* const* d_in, const int* in_sizes, int n_in,
                              void* d_out, int out_size, void* d_ws, size_t ws_size,
                              hipStream_t stream) {
    const float* x = (const float*)d_in[0];
    const int* ei = (const int*)d_in[1];     // int32 per harness contract
    const float* ew = (const float*)d_in[2];
    const float* W = (const float*)d_in[3];
    const float* bias = (const float*)d_in[4];
    float* out = (float*)d_out;

    const int N = in_sizes[0] / FEAT;   // 50000
    const int E = in_sizes[1] / 2;      // 1600000
    const int NB = (N + SCB - 1) / SCB;
    const int rchunk = (N + 7) / 8;

    char* p = (char*)d_ws;
    auto alloc = [&](size_t bytes) {
        char* q = p;
        p += (bytes + 255) & ~(size_t)255;
        return q;
    };
    int* cnt = (int*)alloc((size_t)N * 4);
    int* offsets = (int*)alloc(((size_t)N + 1) * 4);
    int* cursor = (int*)alloc((size_t)N * 4);
    float* dinv = (float*)alloc((size_t)N * 4);
    int* partial = (int*)alloc((size_t)N * 4);
    int* blockSums = (int*)alloc((size_t)NB * 4);
    int* blockOffsets = (int*)alloc((size_t)NB * 4);
    uint* csr = (uint*)alloc((size_t)E * 4);
    ushort* xb = (ushort*)alloc((size_t)N * FEAT * 2);
    ushort* Ab = (ushort*)alloc((size_t)N * FEAT * 2);
    ushort* Bb = (ushort*)alloc((size_t)N * FEAT * 2);
    (void)ws_size;

    hipMemsetAsync(cnt, 0, (size_t)N * 4, stream);
    hipMemsetAsync(cursor, 0, (size_t)N * 4, stream);

    int fgrid = ((E + FILLCH - 1) / FILLCH) * 8;
    count_kernel<<<fgrid, 256, 0, stream>>>(ei, E, cnt, rchunk);
    scan1_kernel<<<NB, SCB, 0, stream>>>(cnt, partial, blockSums, dinv, N);
    scan2_kernel<<<1, SCB, 0, stream>>>(blockSums, blockOffsets, NB, offsets + N);
    scan3_kernel<<<NB, SCB, 0, stream>>>(partial, blockOffsets, offsets, N);
    fill_kernel<<<fgrid, 256, 0, stream>>>(ei, ew, offsets, cursor, dinv, csr, E, rchunk);

    // out = bias + x*W0 ; xb = bf16(x)
    cvt_einsum0_kernel<<<(N + 7) / 8, 256, 0, stream>>>(x, xb, W, bias, out, N);

    int sg = (N + WPB - 1) / WPB;
    // Tx1 = S(x);            out += Tx1*W1
    spmm_fused_kernel<<<sg, 512, 0, stream>>>(xb, nullptr, Ab, offsets, csr,
                                              W + 1 * FEAT * GOUT, out, N, 0);
    // Tx2 = 2*S(Tx1) - x;    out += Tx2*W2
    spmm_fused_kernel<<<sg, 512, 0, stream>>>(Ab, xb, Bb, offsets, csr,
                                              W + 2 * FEAT * GOUT, out, N, 1);
    // Tx3 = 2*S(Tx2) - Tx1;  out += Tx3*W3   (outb aliases sub; read-before-write)
    spmm_fused_kernel<<<sg, 512, 0, stream>>>(Bb, Ab, Ab, offsets, csr,
                                              W + 3 * FEAT * GOUT, out, N, 1);
}

// Round 6
// 471.331 us; speedup vs baseline: 1.1625x; 1.1625x over previous
//
#include <hip/hip_runtime.h>

// ChebTimeConv: N=50000, E=1.6M, H=4, F_IN=F_OUT=32, K=4, Q=1.
// CSR build is a two-phase binned counting sort:
//   bin_kernel:    edges -> 8B staging records in per-(block,bucket) runs
//                  (bucket = row>>8; coalesced run writes; per-row cnt atomics)
//   scan1/2/3:     cnt -> offsets, dinv
//   scatter_kernel: per bucket, staging -> LDS window -> coalesced csr write
// CSR entry packed 4B: (col<<16)|bf16(lap). SpMM: one wave/node, unroll-8
// gather over bf16 mirrors, fused einsum epilogue (padded LDS).
// staging aliases Ab/Bb (dead before first spmm). edge_index arrives int32.

#define FEAT 128   // H * F_IN
#define GOUT 32    // F_OUT
#define SCB 256
#define WPB 8
#define CH 4096    // edges per bin block
#define WCAP 16384 // scatter LDS window entries
#define CAP 12032  // staging slots per bucket (mean 7908, +46 sigma)
#define TROW 160   // padded LDS row: +4 floats per 16

typedef unsigned int uint;
typedef unsigned short ushort;

__device__ __forceinline__ ushort f2bf(float f) {
    uint u = __float_as_uint(f);
    return (ushort)((u + 0x7fffu + ((u >> 16) & 1u)) >> 16);   // RNE
}
__device__ __forceinline__ float bflo(uint u) { return __uint_as_float(u << 16); }
__device__ __forceinline__ float bfhi(uint u) { return __uint_as_float(u & 0xffff0000u); }
__device__ __forceinline__ int tidx(int i) { return i + ((i >> 4) << 2); }

// ---- phase 1: bin edges into per-(block,bucket) staging runs + count ----
__global__ __launch_bounds__(256) void bin_kernel(
    const int* __restrict__ ei, const float* __restrict__ ew, int E,
    int* __restrict__ cnt, int* __restrict__ bucketCursor,
    uint2* __restrict__ staging) {
    __shared__ int hist[256];
    __shared__ int base[256];
    int e0 = blockIdx.x * CH;
    int e1 = min(e0 + CH, E);
    int t = threadIdx.x;
    hist[t] = 0;
    __syncthreads();
    for (int e = e0 + t; e < e1; e += 256) {
        int r = ei[e], c = ei[(size_t)E + e];
        if (r != c) {
            atomicAdd(&hist[r >> 8], 1);
            atomicAdd(&cnt[r], 1);
        }
    }
    __syncthreads();
    int h = hist[t];
    if (h > 0) {
        int run = atomicAdd(&bucketCursor[t], h);
        base[t] = t * CAP + run;
    }
    __syncthreads();
    hist[t] = 0;
    __syncthreads();
    for (int e = e0 + t; e < e1; e += 256) {
        int r = ei[e], c = ei[(size_t)E + e];
        if (r == c) continue;
        float w = ew[e];
        int bk = r >> 8;
        int j = atomicAdd(&hist[bk], 1);
        int idx = base[bk] + j;
        if (idx < (bk + 1) * CAP)   // impossible-overflow guard
            staging[idx] = make_uint2(__float_as_uint(w), ((uint)c << 16) | (uint)(r & 255));
    }
}

// ---- two-level scan (dinv folded into scan1) ----
__global__ void scan1_kernel(const int* __restrict__ cnt, int* __restrict__ partial,
                             int* __restrict__ blockSums, float* __restrict__ dinv, int n) {
    __shared__ int buf[2][SCB];
    int t = threadIdx.x;
    int i = blockIdx.x * SCB + t;
    int v = (i < n) ? cnt[i] : 0;
    if (i < n) dinv[i] = (v > 0) ? rsqrtf((float)v) : 0.0f;
    buf[0][t] = v;
    __syncthreads();
    int src = 0;
    for (int off = 1; off < SCB; off <<= 1) {
        int d = src ^ 1;
        buf[d][t] = buf[src][t] + ((t >= off) ? buf[src][t - off] : 0);
        __syncthreads();
        src = d;
    }
    int incl = buf[src][t];
    if (i < n) partial[i] = incl - v;
    if (t == SCB - 1) blockSums[blockIdx.x] = incl;
}

__global__ void scan2_kernel(const int* __restrict__ blockSums, int* __restrict__ blockOffsets,
                             int nb, int* __restrict__ total_out) {
    __shared__ int buf[2][SCB];
    __shared__ int carry_s;
    if (threadIdx.x == 0) carry_s = 0;
    __syncthreads();
    for (int base = 0; base < nb; base += SCB) {
        int i = base + (int)threadIdx.x;
        int v = (i < nb) ? blockSums[i] : 0;
        buf[0][threadIdx.x] = v;
        __syncthreads();
        int src = 0;
        for (int off = 1; off < SCB; off <<= 1) {
            int d = src ^ 1;
            buf[d][threadIdx.x] = buf[src][threadIdx.x] +
                                  ((threadIdx.x >= (unsigned)off) ? buf[src][threadIdx.x - off] : 0);
            __syncthreads();
            src = d;
        }
        int incl = buf[src][threadIdx.x];
        int c = carry_s;
        if (i < nb) blockOffsets[i] = c + incl - v;
        __syncthreads();
        if (threadIdx.x == SCB - 1) carry_s = c + incl;
        __syncthreads();
    }
    if (threadIdx.x == 0) *total_out = carry_s;
}

__global__ void scan3_kernel(const int* __restrict__ partial, const int* __restrict__ blockOffsets,
                             int* __restrict__ offsets, int n) {
    int i = blockIdx.x * blockDim.x + threadIdx.x;
    if (i < n) offsets[i] = partial[i] + blockOffsets[i / SCB];
}

// ---- phase 2: per-bucket scatter via LDS window -> coalesced csr write ----
__global__ __launch_bounds__(256) void scatter_kernel(
    const uint2* __restrict__ staging, const int* __restrict__ bucketCursor,
    const int* __restrict__ offsets, const float* __restrict__ dinv,
    uint* __restrict__ csr, int n) {
    __shared__ uint win[WCAP];          // 64 KB
    __shared__ int roff[256];
    __shared__ int rcur[256];
    __shared__ float dloc[256];
    int b = blockIdx.x;
    int r0 = b << 8;
    int nrows = min(256, n - r0);
    int t = threadIdx.x;
    if (t < nrows) {
        roff[t] = offsets[r0 + t];
        dloc[t] = dinv[r0 + t];
    }
    rcur[t] = 0;
    __syncthreads();
    int wbeg = roff[0];
    int nrec = bucketCursor[b];
    bool fit = (nrec <= WCAP);
    const uint2* src = staging + (size_t)b * CAP;
    for (int k = t; k < nrec; k += 256) {
        uint2 rec = src[k];
        int col = rec.y >> 16;
        int rl = rec.y & 255;
        float lap = -dloc[rl] * __uint_as_float(rec.x) * dinv[col];
        uint colap = ((uint)col << 16) | (uint)f2bf(lap);
        int pos = roff[rl] + atomicAdd(&rcur[rl], 1);
        if (fit) win[pos - wbeg] = colap;
        else csr[pos] = colap;
    }
    __syncthreads();
    if (fit)
        for (int k = t; k < nrec; k += 256) csr[wbeg + k] = win[k];
}

// ---- fused: x -> bf16 mirror, plus out = bias + x*W0 ----
__global__ __launch_bounds__(256) void cvt_einsum0_kernel(
    const float* __restrict__ x, ushort* __restrict__ xb,
    const float* __restrict__ W0, const float* __restrict__ bias,
    float* __restrict__ out, int n) {
    __shared__ __align__(16) float4 sW4[FEAT * GOUT / 4];
    __shared__ __align__(16) float sT[8 * TROW];
    const float* sW = (const float*)sW4;
    int t = threadIdx.x;
    const float4* wsrc = (const float4*)W0;
    for (int idx = t; idx < FEAT * GOUT / 4; idx += 256) sW4[idx] = wsrc[idx];
    size_t gi = (size_t)blockIdx.x * (8 * FEAT) + (size_t)t * 4;
    float4 v = make_float4(0.f, 0.f, 0.f, 0.f);
    bool inb = gi < (size_t)n * FEAT;
    if (inb) {
        v = *(const float4*)(x + gi);
        ushort4 o;
        o.x = f2bf(v.x); o.y = f2bf(v.y); o.z = f2bf(v.z); o.w = f2bf(v.w);
        *(ushort4*)(xb + gi) = o;
    }
    int nl = t >> 5;
    int f0 = 4 * (t & 31);
    *(float4*)&sT[nl * TROW + tidx(f0)] = v;
    __syncthreads();
    int l32 = t & 31;
    int q = l32 & 7;
    int part = l32 >> 3;
    float4 a4 = make_float4(0.f, 0.f, 0.f, 0.f);
#pragma unroll
    for (int j = 0; j < 8; ++j) {
        float4 t4 = *(const float4*)&sT[nl * TROW + tidx(part * 32 + 4 * j)];
        const float* wv0 = &sW[(part * 32 + 4 * j) * GOUT + 4 * q];
        float4 w0 = *(const float4*)(wv0);
        float4 w1 = *(const float4*)(wv0 + GOUT);
        float4 w2 = *(const float4*)(wv0 + 2 * GOUT);
        float4 w3 = *(const float4*)(wv0 + 3 * GOUT);
        a4.x += t4.x * w0.x + t4.y * w1.x + t4.z * w2.x + t4.w * w3.x;
        a4.y += t4.x * w0.y + t4.y * w1.y + t4.z * w2.y + t4.w * w3.y;
        a4.z += t4.x * w0.z + t4.y * w1.z + t4.z * w2.z + t4.w * w3.z;
        a4.w += t4.x * w0.w + t4.y * w1.w + t4.z * w2.w + t4.w * w3.w;
    }
    a4.x += __shfl_down(a4.x, 8);  a4.y += __shfl_down(a4.y, 8);
    a4.z += __shfl_down(a4.z, 8);  a4.w += __shfl_down(a4.w, 8);
    a4.x += __shfl_down(a4.x, 16); a4.y += __shfl_down(a4.y, 16);
    a4.z += __shfl_down(a4.z, 16); a4.w += __shfl_down(a4.w, 16);
    int node = blockIdx.x * 8 + nl;
    if (part == 0 && node < n) {
        const float4 b4 = *(const float4*)(bias + 4 * q);
        float4 r;
        r.x = a4.x + b4.x; r.y = a4.y + b4.y; r.z = a4.z + b4.z; r.w = a4.w + b4.w;
        *(float4*)(out + (size_t)node * GOUT + 4 * q) = r;
    }
}

// ---- SpMM (one wave per node, unroll-8 gather) + fused einsum epilogue ----
__global__ __launch_bounds__(512) void spmm_fused_kernel(
    const ushort* __restrict__ inb, const ushort* __restrict__ sub,
    ushort* __restrict__ outb, const int* __restrict__ offsets,
    const uint* __restrict__ csr, const float* __restrict__ Wk,
    float* __restrict__ out, int n, int has_sub) {
    __shared__ __align__(16) float4 sW4[FEAT * GOUT / 4];   // 16 KB
    __shared__ __align__(16) float sT[WPB][TROW];           // 5 KB (padded)
    const float* sW = (const float*)sW4;
    int w = threadIdx.x >> 6;
    int lane = threadIdx.x & 63;
    int node = blockIdx.x * WPB + w;
    const float4* wsrc = (const float4*)Wk;
    for (int idx = threadIdx.x; idx < FEAT * GOUT / 4; idx += 512) sW4[idx] = wsrc[idx];
    float ox = 0.f, oy = 0.f;
    if (node < n) {
        int beg = offsets[node], end = offsets[node + 1];
        float ax = 0.f, ay = 0.f;
        int j = beg;
        for (; j + 8 <= end; j += 8) {
            uint q[8], u[8];
#pragma unroll
            for (int k = 0; k < 8; ++k) q[k] = __builtin_nontemporal_load(csr + j + k);
#pragma unroll
            for (int k = 0; k < 8; ++k)
                u[k] = ((const uint*)(inb + (size_t)(q[k] >> 16) * FEAT))[lane];
#pragma unroll
            for (int k = 0; k < 8; ++k) {
                float l = bflo(q[k]);
                ax += l * bflo(u[k]);
                ay += l * bfhi(u[k]);
            }
        }
        for (; j < end; ++j) {
            uint qe = __builtin_nontemporal_load(csr + j);
            uint u = ((const uint*)(inb + (size_t)(qe >> 16) * FEAT))[lane];
            float l = bflo(qe);
            ax += l * bflo(u);
            ay += l * bfhi(u);
        }
        ox = ax; oy = ay;
        if (has_sub) {
            uint s = __builtin_nontemporal_load((const uint*)(sub + (size_t)node * FEAT) + lane);
            ox = 2.f * ax - bflo(s);
            oy = 2.f * ay - bfhi(s);
        }
        uint o = (uint)f2bf(ox) | ((uint)f2bf(oy) << 16);
        __builtin_nontemporal_store(o, (uint*)(outb + (size_t)node * FEAT) + lane);
    }
    *(float2*)&sT[w][tidx(2 * lane)] = make_float2(ox, oy);
    __syncthreads();
    int q = lane & 7;
    int part = lane >> 3;
    float4 a4 = make_float4(0.f, 0.f, 0.f, 0.f);
#pragma unroll
    for (int j = 0; j < 4; ++j) {
        float4 t4 = *(const float4*)&sT[w][20 * part + 4 * j];   // tidx(16p+4j)
        const float* wv0 = &sW[(part * 16 + 4 * j) * GOUT + 4 * q];
        float4 w0 = *(const float4*)(wv0);
        float4 w1 = *(const float4*)(wv0 + GOUT);
        float4 w2 = *(const float4*)(wv0 + 2 * GOUT);
        float4 w3 = *(const float4*)(wv0 + 3 * GOUT);
        a4.x += t4.x * w0.x + t4.y * w1.x + t4.z * w2.x + t4.w * w3.x;
        a4.y += t4.x * w0.y + t4.y * w1.y + t4.z * w2.y + t4.w * w3.y;
        a4.z += t4.x * w0.z + t4.y * w1.z + t4.z * w2.z + t4.w * w3.z;
        a4.w += t4.x * w0.w + t4.y * w1.w + t4.z * w2.w + t4.w * w3.w;
    }
#pragma unroll
    for (int off = 8; off < 64; off <<= 1) {
        a4.x += __shfl_down(a4.x, off);
        a4.y += __shfl_down(a4.y, off);
        a4.z += __shfl_down(a4.z, off);
        a4.w += __shfl_down(a4.w, off);
    }
    if (part == 0 && node < n) {
        float4* po = (float4*)(out + (size_t)node * GOUT + 4 * q);
        float4 cur = *po;
        cur.x += a4.x; cur.y += a4.y; cur.z += a4.z; cur.w += a4.w;
        *po = cur;
    }
}

extern "C" void kernel_launch(void* const* d_in, const int* in_sizes, int n_in,
                              void* d_out, int out_size, void* d_ws, size_t ws_size,
                              hipStream_t stream) {
    const float* x = (const float*)d_in[0];
    const int* ei = (const int*)d_in[1];     // int32 per harness contract
    const float* ew = (const float*)d_in[2];
    const float* W = (const float*)d_in[3];
    const float* bias = (const float*)d_in[4];
    float* out = (float*)d_out;

    const int N = in_sizes[0] / FEAT;   // 50000
    const int E = in_sizes[1] / 2;      // 1600000
    const int NB = (N + SCB - 1) / SCB;
    const int NBUK = (N + 255) >> 8;    // 196

    char* p = (char*)d_ws;
    auto alloc = [&](size_t bytes) {
        char* q = p;
        p += (bytes + 255) & ~(size_t)255;
        return q;
    };
    int* cnt = (int*)alloc((size_t)N * 4);
    int* offsets = (int*)alloc(((size_t)N + 1) * 4);
    float* dinv = (float*)alloc((size_t)N * 4);
    int* partial = (int*)alloc((size_t)N * 4);
    int* blockSums = (int*)alloc((size_t)NB * 4);
    int* blockOffsets = (int*)alloc((size_t)NB * 4);
    int* bucketCursor = (int*)alloc((size_t)NBUK * 4);
    uint* csr = (uint*)alloc((size_t)E * 4);
    ushort* xb = (ushort*)alloc((size_t)N * FEAT * 2);
    ushort* Ab = (ushort*)alloc((size_t)N * FEAT * 2);
    ushort* Bb = (ushort*)alloc((size_t)N * FEAT * 2);
    uint2* staging = (uint2*)Ab;   // aliases Ab+Bb (dead before first spmm);
                                   // needs NBUK*CAP*8 = 18.9 MB <= 25.6 MB
    (void)ws_size;

    hipMemsetAsync(cnt, 0, (size_t)N * 4, stream);
    hipMemsetAsync(bucketCursor, 0, (size_t)NBUK * 4, stream);

    bin_kernel<<<(E + CH - 1) / CH, 256, 0, stream>>>(ei, ew, E, cnt, bucketCursor, staging);
    scan1_kernel<<<NB, SCB, 0, stream>>>(cnt, partial, blockSums, dinv, N);
    scan2_kernel<<<1, SCB, 0, stream>>>(blockSums, blockOffsets, NB, offsets + N);
    scan3_kernel<<<NB, SCB, 0, stream>>>(partial, blockOffsets, offsets, N);
    scatter_kernel<<<NBUK, 256, 0, stream>>>(staging, bucketCursor, offsets, dinv, csr, N);

    // out = bias + x*W0 ; xb = bf16(x)
    cvt_einsum0_kernel<<<(N + 7) / 8, 256, 0, stream>>>(x, xb, W, bias, out, N);

    int sg = (N + WPB - 1) / WPB;
    // Tx1 = S(x);            out += Tx1*W1
    spmm_fused_kernel<<<sg, 512, 0, stream>>>(xb, nullptr, Ab, offsets, csr,
                                              W + 1 * FEAT * GOUT, out, N, 0);
    // Tx2 = 2*S(Tx1) - x;    out += Tx2*W2
    spmm_fused_kernel<<<sg, 512, 0, stream>>>(Ab, xb, Bb, offsets, csr,
                                              W + 2 * FEAT * GOUT, out, N, 1);
    // Tx3 = 2*S(Tx2) - Tx1;  out += Tx3*W3   (outb aliases sub; read-before-write)
    spmm_fused_kernel<<<sg, 512, 0, stream>>>(Bb, Ab, Ab, offsets, csr,
                                              W + 3 * FEAT * GOUT, out, N, 1);
}

// Round 7
// 407.373 us; speedup vs baseline: 1.3451x; 1.1570x over previous
//
#include <hip/hip_runtime.h>

// ChebTimeConv: N=50000, E=1.6M, H=4, F_IN=F_OUT=32, K=4, Q=1.
// CSR build: binned counting sort.
//   bin_kernel (1024 thr):  edges -> 8B staging records in per-(block,bucket)
//                           runs (bucket = row>>8). No global atomics per edge.
//   bucket_count_kernel:    staging -> per-row cnt (contiguous reads, LDS hist)
//   scan1/2/3:              cnt -> offsets, dinv
//   scatter_kernel:         per bucket, staging -> LDS window -> coalesced csr
// CSR entry packed 4B: (col<<16)|bf16(lap). SpMM: one wave/node, unroll-8
// gather over bf16 mirrors, fused einsum epilogue (padded LDS).
// staging aliases Ab/Bb (dead before first spmm). edge_index arrives int32.

#define FEAT 128   // H * F_IN
#define GOUT 32    // F_OUT
#define SCB 256
#define WPB 8
#define CH 4096    // edges per bin block
#define WCAP 16384 // scatter LDS window entries
#define CAP 12032  // staging slots per bucket (mean 7908, +46 sigma)
#define TROW 160   // padded LDS row: +4 floats per 16

typedef unsigned int uint;
typedef unsigned short ushort;

__device__ __forceinline__ ushort f2bf(float f) {
    uint u = __float_as_uint(f);
    return (ushort)((u + 0x7fffu + ((u >> 16) & 1u)) >> 16);   // RNE
}
__device__ __forceinline__ float bflo(uint u) { return __uint_as_float(u << 16); }
__device__ __forceinline__ float bfhi(uint u) { return __uint_as_float(u & 0xffff0000u); }
__device__ __forceinline__ int tidx(int i) { return i + ((i >> 4) << 2); }

// ---- phase 1: bin edges into per-(block,bucket) staging runs ----
__global__ __launch_bounds__(1024) void bin_kernel(
    const int* __restrict__ ei, const float* __restrict__ ew, int E,
    int* __restrict__ bucketCursor, uint2* __restrict__ staging) {
    __shared__ int hist[256];
    __shared__ int base[256];
    int e0 = blockIdx.x * CH;
    int e1 = min(e0 + CH, E);
    int t = threadIdx.x;
    if (t < 256) hist[t] = 0;
    __syncthreads();
    for (int e = e0 + t; e < e1; e += 1024) {
        int r = ei[e], c = ei[(size_t)E + e];
        if (r != c) atomicAdd(&hist[r >> 8], 1);
    }
    __syncthreads();
    if (t < 256) {
        int h = hist[t];
        if (h > 0) {
            int run = atomicAdd(&bucketCursor[t], h);
            base[t] = t * CAP + run;
        }
        hist[t] = 0;
    }
    __syncthreads();
    for (int e = e0 + t; e < e1; e += 1024) {
        int r = ei[e], c = ei[(size_t)E + e];
        if (r == c) continue;
        float w = ew[e];
        int bk = r >> 8;
        int j = atomicAdd(&hist[bk], 1);
        int idx = base[bk] + j;
        if (idx < (bk + 1) * CAP)   // impossible-overflow guard
            staging[idx] = make_uint2(__float_as_uint(w), ((uint)c << 16) | (uint)(r & 255));
    }
}

// ---- per-row counts from staging (contiguous reads, LDS hist, no atomics) ----
__global__ __launch_bounds__(256) void bucket_count_kernel(
    const uint2* __restrict__ staging, const int* __restrict__ bucketCursor,
    int* __restrict__ cnt, int n) {
    __shared__ int hist[256];
    int b = blockIdx.x;
    int t = threadIdx.x;
    hist[t] = 0;
    __syncthreads();
    int nrec = bucketCursor[b];
    const uint2* src = staging + (size_t)b * CAP;
    for (int k = t; k < nrec; k += 256)
        atomicAdd(&hist[src[k].y & 255], 1);
    __syncthreads();
    int r = (b << 8) + t;
    if (r < n) cnt[r] = hist[t];
}

// ---- two-level scan (dinv folded into scan1) ----
__global__ void scan1_kernel(const int* __restrict__ cnt, int* __restrict__ partial,
                             int* __restrict__ blockSums, float* __restrict__ dinv, int n) {
    __shared__ int buf[2][SCB];
    int t = threadIdx.x;
    int i = blockIdx.x * SCB + t;
    int v = (i < n) ? cnt[i] : 0;
    if (i < n) dinv[i] = (v > 0) ? rsqrtf((float)v) : 0.0f;
    buf[0][t] = v;
    __syncthreads();
    int src = 0;
    for (int off = 1; off < SCB; off <<= 1) {
        int d = src ^ 1;
        buf[d][t] = buf[src][t] + ((t >= off) ? buf[src][t - off] : 0);
        __syncthreads();
        src = d;
    }
    int incl = buf[src][t];
    if (i < n) partial[i] = incl - v;
    if (t == SCB - 1) blockSums[blockIdx.x] = incl;
}

__global__ void scan2_kernel(const int* __restrict__ blockSums, int* __restrict__ blockOffsets,
                             int nb, int* __restrict__ total_out) {
    __shared__ int buf[2][SCB];
    __shared__ int carry_s;
    if (threadIdx.x == 0) carry_s = 0;
    __syncthreads();
    for (int base = 0; base < nb; base += SCB) {
        int i = base + (int)threadIdx.x;
        int v = (i < nb) ? blockSums[i] : 0;
        buf[0][threadIdx.x] = v;
        __syncthreads();
        int src = 0;
        for (int off = 1; off < SCB; off <<= 1) {
            int d = src ^ 1;
            buf[d][threadIdx.x] = buf[src][threadIdx.x] +
                                  ((threadIdx.x >= (unsigned)off) ? buf[src][threadIdx.x - off] : 0);
            __syncthreads();
            src = d;
        }
        int incl = buf[src][threadIdx.x];
        int c = carry_s;
        if (i < nb) blockOffsets[i] = c + incl - v;
        __syncthreads();
        if (threadIdx.x == SCB - 1) carry_s = c + incl;
        __syncthreads();
    }
    if (threadIdx.x == 0) *total_out = carry_s;
}

__global__ void scan3_kernel(const int* __restrict__ partial, const int* __restrict__ blockOffsets,
                             int* __restrict__ offsets, int n) {
    int i = blockIdx.x * blockDim.x + threadIdx.x;
    if (i < n) offsets[i] = partial[i] + blockOffsets[i / SCB];
}

// ---- phase 2: per-bucket scatter via LDS window -> coalesced csr write ----
__global__ __launch_bounds__(256) void scatter_kernel(
    const uint2* __restrict__ staging, const int* __restrict__ bucketCursor,
    const int* __restrict__ offsets, const float* __restrict__ dinv,
    uint* __restrict__ csr, int n) {
    __shared__ uint win[WCAP];          // 64 KB
    __shared__ int roff[256];
    __shared__ int rcur[256];
    __shared__ float dloc[256];
    int b = blockIdx.x;
    int r0 = b << 8;
    int nrows = min(256, n - r0);
    int t = threadIdx.x;
    if (t < nrows) {
        roff[t] = offsets[r0 + t];
        dloc[t] = dinv[r0 + t];
    }
    rcur[t] = 0;
    __syncthreads();
    int wbeg = roff[0];
    int nrec = bucketCursor[b];
    bool fit = (nrec <= WCAP);
    const uint2* src = staging + (size_t)b * CAP;
    for (int k = t; k < nrec; k += 256) {
        uint2 rec = src[k];
        int col = rec.y >> 16;
        int rl = rec.y & 255;
        float lap = -dloc[rl] * __uint_as_float(rec.x) * dinv[col];
        uint colap = ((uint)col << 16) | (uint)f2bf(lap);
        int pos = roff[rl] + atomicAdd(&rcur[rl], 1);
        if (fit) win[pos - wbeg] = colap;
        else csr[pos] = colap;
    }
    __syncthreads();
    if (fit)
        for (int k = t; k < nrec; k += 256) csr[wbeg + k] = win[k];
}

// ---- fused: x -> bf16 mirror, plus out = bias + x*W0 ----
__global__ __launch_bounds__(256) void cvt_einsum0_kernel(
    const float* __restrict__ x, ushort* __restrict__ xb,
    const float* __restrict__ W0, const float* __restrict__ bias,
    float* __restrict__ out, int n) {
    __shared__ __align__(16) float4 sW4[FEAT * GOUT / 4];
    __shared__ __align__(16) float sT[8 * TROW];
    const float* sW = (const float*)sW4;
    int t = threadIdx.x;
    const float4* wsrc = (const float4*)W0;
    for (int idx = t; idx < FEAT * GOUT / 4; idx += 256) sW4[idx] = wsrc[idx];
    size_t gi = (size_t)blockIdx.x * (8 * FEAT) + (size_t)t * 4;
    float4 v = make_float4(0.f, 0.f, 0.f, 0.f);
    bool inb = gi < (size_t)n * FEAT;
    if (inb) {
        v = *(const float4*)(x + gi);
        ushort4 o;
        o.x = f2bf(v.x); o.y = f2bf(v.y); o.z = f2bf(v.z); o.w = f2bf(v.w);
        *(ushort4*)(xb + gi) = o;
    }
    int nl = t >> 5;
    int f0 = 4 * (t & 31);
    *(float4*)&sT[nl * TROW + tidx(f0)] = v;
    __syncthreads();
    int l32 = t & 31;
    int q = l32 & 7;
    int part = l32 >> 3;
    float4 a4 = make_float4(0.f, 0.f, 0.f, 0.f);
#pragma unroll
    for (int j = 0; j < 8; ++j) {
        float4 t4 = *(const float4*)&sT[nl * TROW + tidx(part * 32 + 4 * j)];
        const float* wv0 = &sW[(part * 32 + 4 * j) * GOUT + 4 * q];
        float4 w0 = *(const float4*)(wv0);
        float4 w1 = *(const float4*)(wv0 + GOUT);
        float4 w2 = *(const float4*)(wv0 + 2 * GOUT);
        float4 w3 = *(const float4*)(wv0 + 3 * GOUT);
        a4.x += t4.x * w0.x + t4.y * w1.x + t4.z * w2.x + t4.w * w3.x;
        a4.y += t4.x * w0.y + t4.y * w1.y + t4.z * w2.y + t4.w * w3.y;
        a4.z += t4.x * w0.z + t4.y * w1.z + t4.z * w2.z + t4.w * w3.z;
        a4.w += t4.x * w0.w + t4.y * w1.w + t4.z * w2.w + t4.w * w3.w;
    }
    a4.x += __shfl_down(a4.x, 8);  a4.y += __shfl_down(a4.y, 8);
    a4.z += __shfl_down(a4.z, 8);  a4.w += __shfl_down(a4.w, 8);
    a4.x += __shfl_down(a4.x, 16); a4.y += __shfl_down(a4.y, 16);
    a4.z += __shfl_down(a4.z, 16); a4.w += __shfl_down(a4.w, 16);
    int node = blockIdx.x * 8 + nl;
    if (part == 0 && node < n) {
        const float4 b4 = *(const float4*)(bias + 4 * q);
        float4 r;
        r.x = a4.x + b4.x; r.y = a4.y + b4.y; r.z = a4.z + b4.z; r.w = a4.w + b4.w;
        *(float4*)(out + (size_t)node * GOUT + 4 * q) = r;
    }
}

// ---- SpMM (one wave per node, unroll-8 gather) + fused einsum epilogue ----
__global__ __launch_bounds__(512) void spmm_fused_kernel(
    const ushort* __restrict__ inb, const ushort* __restrict__ sub,
    ushort* __restrict__ outb, const int* __restrict__ offsets,
    const uint* __restrict__ csr, const float* __restrict__ Wk,
    float* __restrict__ out, int n, int has_sub) {
    __shared__ __align__(16) float4 sW4[FEAT * GOUT / 4];   // 16 KB
    __shared__ __align__(16) float sT[WPB][TROW];           // 5 KB (padded)
    const float* sW = (const float*)sW4;
    int w = threadIdx.x >> 6;
    int lane = threadIdx.x & 63;
    int node = blockIdx.x * WPB + w;
    const float4* wsrc = (const float4*)Wk;
    for (int idx = threadIdx.x; idx < FEAT * GOUT / 4; idx += 512) sW4[idx] = wsrc[idx];
    float ox = 0.f, oy = 0.f;
    if (node < n) {
        int beg = offsets[node], end = offsets[node + 1];
        float ax = 0.f, ay = 0.f;
        int j = beg;
        for (; j + 8 <= end; j += 8) {
            uint q[8], u[8];
#pragma unroll
            for (int k = 0; k < 8; ++k) q[k] = __builtin_nontemporal_load(csr + j + k);
#pragma unroll
            for (int k = 0; k < 8; ++k)
                u[k] = ((const uint*)(inb + (size_t)(q[k] >> 16) * FEAT))[lane];
#pragma unroll
            for (int k = 0; k < 8; ++k) {
                float l = bflo(q[k]);
                ax += l * bflo(u[k]);
                ay += l * bfhi(u[k]);
            }
        }
        for (; j < end; ++j) {
            uint qe = __builtin_nontemporal_load(csr + j);
            uint u = ((const uint*)(inb + (size_t)(qe >> 16) * FEAT))[lane];
            float l = bflo(qe);
            ax += l * bflo(u);
            ay += l * bfhi(u);
        }
        ox = ax; oy = ay;
        if (has_sub) {
            uint s = __builtin_nontemporal_load((const uint*)(sub + (size_t)node * FEAT) + lane);
            ox = 2.f * ax - bflo(s);
            oy = 2.f * ay - bfhi(s);
        }
        uint o = (uint)f2bf(ox) | ((uint)f2bf(oy) << 16);
        __builtin_nontemporal_store(o, (uint*)(outb + (size_t)node * FEAT) + lane);
    }
    *(float2*)&sT[w][tidx(2 * lane)] = make_float2(ox, oy);
    __syncthreads();
    int q = lane & 7;
    int part = lane >> 3;
    float4 a4 = make_float4(0.f, 0.f, 0.f, 0.f);
#pragma unroll
    for (int j = 0; j < 4; ++j) {
        float4 t4 = *(const float4*)&sT[w][20 * part + 4 * j];   // tidx(16p+4j)
        const float* wv0 = &sW[(part * 16 + 4 * j) * GOUT + 4 * q];
        float4 w0 = *(const float4*)(wv0);
        float4 w1 = *(const float4*)(wv0 + GOUT);
        float4 w2 = *(const float4*)(wv0 + 2 * GOUT);
        float4 w3 = *(const float4*)(wv0 + 3 * GOUT);
        a4.x += t4.x * w0.x + t4.y * w1.x + t4.z * w2.x + t4.w * w3.x;
        a4.y += t4.x * w0.y + t4.y * w1.y + t4.z * w2.y + t4.w * w3.y;
        a4.z += t4.x * w0.z + t4.y * w1.z + t4.z * w2.z + t4.w * w3.z;
        a4.w += t4.x * w0.w + t4.y * w1.w + t4.z * w2.w + t4.w * w3.w;
    }
#pragma unroll
    for (int off = 8; off < 64; off <<= 1) {
        a4.x += __shfl_down(a4.x, off);
        a4.y += __shfl_down(a4.y, off);
        a4.z += __shfl_down(a4.z, off);
        a4.w += __shfl_down(a4.w, off);
    }
    if (part == 0 && node < n) {
        float4* po = (float4*)(out + (size_t)node * GOUT + 4 * q);
        float4 cur = *po;
        cur.x += a4.x; cur.y += a4.y; cur.z += a4.z; cur.w += a4.w;
        *po = cur;
    }
}

extern "C" void kernel_launch(void* const* d_in, const int* in_sizes, int n_in,
                              void* d_out, int out_size, void* d_ws, size_t ws_size,
                              hipStream_t stream) {
    const float* x = (const float*)d_in[0];
    const int* ei = (const int*)d_in[1];     // int32 per harness contract
    const float* ew = (const float*)d_in[2];
    const float* W = (const float*)d_in[3];
    const float* bias = (const float*)d_in[4];
    float* out = (float*)d_out;

    const int N = in_sizes[0] / FEAT;   // 50000
    const int E = in_sizes[1] / 2;      // 1600000
    const int NB = (N + SCB - 1) / SCB;
    const int NBUK = (N + 255) >> 8;    // 196

    char* p = (char*)d_ws;
    auto alloc = [&](size_t bytes) {
        char* q = p;
        p += (bytes + 255) & ~(size_t)255;
        return q;
    };
    int* cnt = (int*)alloc((size_t)N * 4);
    int* offsets = (int*)alloc(((size_t)N + 1) * 4);
    float* dinv = (float*)alloc((size_t)N * 4);
    int* partial = (int*)alloc((size_t)N * 4);
    int* blockSums = (int*)alloc((size_t)NB * 4);
    int* blockOffsets = (int*)alloc((size_t)NB * 4);
    int* bucketCursor = (int*)alloc((size_t)NBUK * 4);
    uint* csr = (uint*)alloc((size_t)E * 4);
    ushort* xb = (ushort*)alloc((size_t)N * FEAT * 2);
    ushort* Ab = (ushort*)alloc((size_t)N * FEAT * 2);
    ushort* Bb = (ushort*)alloc((size_t)N * FEAT * 2);
    uint2* staging = (uint2*)Ab;   // aliases Ab+Bb (dead before first spmm);
                                   // needs NBUK*CAP*8 = 18.9 MB <= 25.6 MB
    (void)ws_size;

    hipMemsetAsync(bucketCursor, 0, (size_t)NBUK * 4, stream);

    bin_kernel<<<(E + CH - 1) / CH, 1024, 0, stream>>>(ei, ew, E, bucketCursor, staging);
    bucket_count_kernel<<<NBUK, 256, 0, stream>>>(staging, bucketCursor, cnt, N);
    scan1_kernel<<<NB, SCB, 0, stream>>>(cnt, partial, blockSums, dinv, N);
    scan2_kernel<<<1, SCB, 0, stream>>>(blockSums, blockOffsets, NB, offsets + N);
    scan3_kernel<<<NB, SCB, 0, stream>>>(partial, blockOffsets, offsets, N);
    scatter_kernel<<<NBUK, 256, 0, stream>>>(staging, bucketCursor, offsets, dinv, csr, N);

    // out = bias + x*W0 ; xb = bf16(x)
    cvt_einsum0_kernel<<<(N + 7) / 8, 256, 0, stream>>>(x, xb, W, bias, out, N);

    int sg = (N + WPB - 1) / WPB;
    // Tx1 = S(x);            out += Tx1*W1
    spmm_fused_kernel<<<sg, 512, 0, stream>>>(xb, nullptr, Ab, offsets, csr,
                                              W + 1 * FEAT * GOUT, out, N, 0);
    // Tx2 = 2*S(Tx1) - x;    out += Tx2*W2
    spmm_fused_kernel<<<sg, 512, 0, stream>>>(Ab, xb, Bb, offsets, csr,
                                              W + 2 * FEAT * GOUT, out, N, 1);
    // Tx3 = 2*S(Tx2) - Tx1;  out += Tx3*W3   (outb aliases sub; read-before-write)
    spmm_fused_kernel<<<sg, 512, 0, stream>>>(Bb, Ab, Ab, offsets, csr,
                                              W + 3 * FEAT * GOUT, out, N, 1);
}

// Round 8
// 384.129 us; speedup vs baseline: 1.4265x; 1.0605x over previous
//
#include <hip/hip_runtime.h>

// ChebTimeConv: N=50000, E=1.6M, H=4, F_IN=F_OUT=32, K=4, Q=1.
// CSR build: binned counting sort (bin -> bucket_count -> scan -> scatter).
// SpMM: feature-chunked passes. Feature mirrors live in CHUNKED layout
// [chunk j][node][32 feats] bf16 so each pass's gather working set is
// N*64B = 3.2 MB < 4 MiB per-XCD L2. One launch per spmm, grid j-major
// (4 passes); wave = 4 nodes x 16 lanes; per-chunk partial einsum is
// accumulated into out with fp32 atomics. CSR entry: (col<<16)|bf16(lap).
// edge_index arrives int32 (harness contract).

#define FEAT 128   // H * F_IN
#define GOUT 32    // F_OUT
#define NCH 4      // feature chunks
#define CHF 32     // feats per chunk
#define SCB 256
#define CH 4096    // edges per bin block
#define WCAP 16384 // scatter LDS window entries
#define CAP 12032  // staging slots per bucket
#define TROW 160   // padded LDS row for cvt kernel

typedef unsigned int uint;
typedef unsigned short ushort;

__device__ __forceinline__ ushort f2bf(float f) {
    uint u = __float_as_uint(f);
    return (ushort)((u + 0x7fffu + ((u >> 16) & 1u)) >> 16);   // RNE
}
__device__ __forceinline__ float bflo(uint u) { return __uint_as_float(u << 16); }
__device__ __forceinline__ float bfhi(uint u) { return __uint_as_float(u & 0xffff0000u); }
__device__ __forceinline__ int tidx(int i) { return i + ((i >> 4) << 2); }

// ---- phase 1: bin edges into per-(block,bucket) staging runs ----
__global__ __launch_bounds__(1024) void bin_kernel(
    const int* __restrict__ ei, const float* __restrict__ ew, int E,
    int* __restrict__ bucketCursor, uint2* __restrict__ staging) {
    __shared__ int hist[256];
    __shared__ int base[256];
    int e0 = blockIdx.x * CH;
    int e1 = min(e0 + CH, E);
    int t = threadIdx.x;
    if (t < 256) hist[t] = 0;
    __syncthreads();
    for (int e = e0 + t; e < e1; e += 1024) {
        int r = ei[e], c = ei[(size_t)E + e];
        if (r != c) atomicAdd(&hist[r >> 8], 1);
    }
    __syncthreads();
    if (t < 256) {
        int h = hist[t];
        if (h > 0) {
            int run = atomicAdd(&bucketCursor[t], h);
            base[t] = t * CAP + run;
        }
        hist[t] = 0;
    }
    __syncthreads();
    for (int e = e0 + t; e < e1; e += 1024) {
        int r = ei[e], c = ei[(size_t)E + e];
        if (r == c) continue;
        float w = ew[e];
        int bk = r >> 8;
        int j = atomicAdd(&hist[bk], 1);
        int idx = base[bk] + j;
        if (idx < (bk + 1) * CAP)   // impossible-overflow guard
            staging[idx] = make_uint2(__float_as_uint(w), ((uint)c << 16) | (uint)(r & 255));
    }
}

// ---- per-row counts from staging (contiguous reads, LDS hist) ----
__global__ __launch_bounds__(256) void bucket_count_kernel(
    const uint2* __restrict__ staging, const int* __restrict__ bucketCursor,
    int* __restrict__ cnt, int n) {
    __shared__ int hist[256];
    int b = blockIdx.x;
    int t = threadIdx.x;
    hist[t] = 0;
    __syncthreads();
    int nrec = bucketCursor[b];
    const uint2* src = staging + (size_t)b * CAP;
    for (int k = t; k < nrec; k += 256)
        atomicAdd(&hist[src[k].y & 255], 1);
    __syncthreads();
    int r = (b << 8) + t;
    if (r < n) cnt[r] = hist[t];
}

// ---- two-level scan (dinv folded into scan1) ----
__global__ void scan1_kernel(const int* __restrict__ cnt, int* __restrict__ partial,
                             int* __restrict__ blockSums, float* __restrict__ dinv, int n) {
    __shared__ int buf[2][SCB];
    int t = threadIdx.x;
    int i = blockIdx.x * SCB + t;
    int v = (i < n) ? cnt[i] : 0;
    if (i < n) dinv[i] = (v > 0) ? rsqrtf((float)v) : 0.0f;
    buf[0][t] = v;
    __syncthreads();
    int src = 0;
    for (int off = 1; off < SCB; off <<= 1) {
        int d = src ^ 1;
        buf[d][t] = buf[src][t] + ((t >= off) ? buf[src][t - off] : 0);
        __syncthreads();
        src = d;
    }
    int incl = buf[src][t];
    if (i < n) partial[i] = incl - v;
    if (t == SCB - 1) blockSums[blockIdx.x] = incl;
}

__global__ void scan2_kernel(const int* __restrict__ blockSums, int* __restrict__ blockOffsets,
                             int nb, int* __restrict__ total_out) {
    __shared__ int buf[2][SCB];
    __shared__ int carry_s;
    if (threadIdx.x == 0) carry_s = 0;
    __syncthreads();
    for (int base = 0; base < nb; base += SCB) {
        int i = base + (int)threadIdx.x;
        int v = (i < nb) ? blockSums[i] : 0;
        buf[0][threadIdx.x] = v;
        __syncthreads();
        int src = 0;
        for (int off = 1; off < SCB; off <<= 1) {
            int d = src ^ 1;
            buf[d][threadIdx.x] = buf[src][threadIdx.x] +
                                  ((threadIdx.x >= (unsigned)off) ? buf[src][threadIdx.x - off] : 0);
            __syncthreads();
            src = d;
        }
        int incl = buf[src][threadIdx.x];
        int c = carry_s;
        if (i < nb) blockOffsets[i] = c + incl - v;
        __syncthreads();
        if (threadIdx.x == SCB - 1) carry_s = c + incl;
        __syncthreads();
    }
    if (threadIdx.x == 0) *total_out = carry_s;
}

__global__ void scan3_kernel(const int* __restrict__ partial, const int* __restrict__ blockOffsets,
                             int* __restrict__ offsets, int n) {
    int i = blockIdx.x * blockDim.x + threadIdx.x;
    if (i < n) offsets[i] = partial[i] + blockOffsets[i / SCB];
}

// ---- phase 2: per-bucket scatter via LDS window -> coalesced csr write ----
__global__ __launch_bounds__(256) void scatter_kernel(
    const uint2* __restrict__ staging, const int* __restrict__ bucketCursor,
    const int* __restrict__ offsets, const float* __restrict__ dinv,
    uint* __restrict__ csr, int n) {
    __shared__ uint win[WCAP];          // 64 KB
    __shared__ int roff[256];
    __shared__ int rcur[256];
    __shared__ float dloc[256];
    int b = blockIdx.x;
    int r0 = b << 8;
    int nrows = min(256, n - r0);
    int t = threadIdx.x;
    if (t < nrows) {
        roff[t] = offsets[r0 + t];
        dloc[t] = dinv[r0 + t];
    }
    rcur[t] = 0;
    __syncthreads();
    int wbeg = roff[0];
    int nrec = bucketCursor[b];
    bool fit = (nrec <= WCAP);
    const uint2* src = staging + (size_t)b * CAP;
    for (int k = t; k < nrec; k += 256) {
        uint2 rec = src[k];
        int col = rec.y >> 16;
        int rl = rec.y & 255;
        float lap = -dloc[rl] * __uint_as_float(rec.x) * dinv[col];
        uint colap = ((uint)col << 16) | (uint)f2bf(lap);
        int pos = roff[rl] + atomicAdd(&rcur[rl], 1);
        if (fit) win[pos - wbeg] = colap;
        else csr[pos] = colap;
    }
    __syncthreads();
    if (fit)
        for (int k = t; k < nrec; k += 256) csr[wbeg + k] = win[k];
}

// ---- fused: x -> CHUNKED bf16 mirror, plus out = bias + x*W0 ----
__global__ __launch_bounds__(256) void cvt_einsum0_kernel(
    const float* __restrict__ x, ushort* __restrict__ xb,
    const float* __restrict__ W0, const float* __restrict__ bias,
    float* __restrict__ out, int n) {
    __shared__ __align__(16) float4 sW4[FEAT * GOUT / 4];
    __shared__ __align__(16) float sT[8 * TROW];
    const float* sW = (const float*)sW4;
    int t = threadIdx.x;
    const float4* wsrc = (const float4*)W0;
    for (int idx = t; idx < FEAT * GOUT / 4; idx += 256) sW4[idx] = wsrc[idx];
    int node = blockIdx.x * 8 + (t >> 5);
    int f0 = 4 * (t & 31);
    float4 v = make_float4(0.f, 0.f, 0.f, 0.f);
    if (node < n) {
        v = *(const float4*)(x + (size_t)node * FEAT + f0);
        ushort4 o;
        o.x = f2bf(v.x); o.y = f2bf(v.y); o.z = f2bf(v.z); o.w = f2bf(v.w);
        int j0 = f0 >> 5;                 // chunk of these 4 feats
        *(ushort4*)(xb + ((size_t)j0 * n + node) * CHF + (f0 & 31)) = o;
    }
    int nl = t >> 5;
    *(float4*)&sT[nl * TROW + tidx(f0)] = v;
    __syncthreads();
    int l32 = t & 31;
    int q = l32 & 7;
    int part = l32 >> 3;
    float4 a4 = make_float4(0.f, 0.f, 0.f, 0.f);
#pragma unroll
    for (int j = 0; j < 8; ++j) {
        float4 t4 = *(const float4*)&sT[nl * TROW + tidx(part * 32 + 4 * j)];
        const float* wv0 = &sW[(part * 32 + 4 * j) * GOUT + 4 * q];
        float4 w0 = *(const float4*)(wv0);
        float4 w1 = *(const float4*)(wv0 + GOUT);
        float4 w2 = *(const float4*)(wv0 + 2 * GOUT);
        float4 w3 = *(const float4*)(wv0 + 3 * GOUT);
        a4.x += t4.x * w0.x + t4.y * w1.x + t4.z * w2.x + t4.w * w3.x;
        a4.y += t4.x * w0.y + t4.y * w1.y + t4.z * w2.y + t4.w * w3.y;
        a4.z += t4.x * w0.z + t4.y * w1.z + t4.z * w2.z + t4.w * w3.z;
        a4.w += t4.x * w0.w + t4.y * w1.w + t4.z * w2.w + t4.w * w3.w;
    }
    a4.x += __shfl_down(a4.x, 8);  a4.y += __shfl_down(a4.y, 8);
    a4.z += __shfl_down(a4.z, 8);  a4.w += __shfl_down(a4.w, 8);
    a4.x += __shfl_down(a4.x, 16); a4.y += __shfl_down(a4.y, 16);
    a4.z += __shfl_down(a4.z, 16); a4.w += __shfl_down(a4.w, 16);
    if (part == 0 && node < n) {
        const float4 b4 = *(const float4*)(bias + 4 * q);
        float4 r;
        r.x = a4.x + b4.x; r.y = a4.y + b4.y; r.z = a4.z + b4.z; r.w = a4.w + b4.w;
        *(float4*)(out + (size_t)node * GOUT + 4 * q) = r;
    }
}

// ---- chunked SpMM pass + partial einsum ----
// grid = NCH * nbj (j-major). Wave = 4 nodes x 16 lanes (u = uint of chunk).
// outb_c[j][node] = chunk j of (S(in) or 2*S(in)-sub); out += T_chunk . W_chunk
__global__ __launch_bounds__(512) void spmm_chunk_kernel(
    const ushort* __restrict__ inb, const ushort* __restrict__ sub,
    ushort* __restrict__ outb, const int* __restrict__ offsets,
    const uint* __restrict__ csr, const float* __restrict__ Wk,
    float* __restrict__ out, int n, int has_sub, int nbj) {
    __shared__ __align__(16) float sW[CHF * GOUT];   // 4 KB: W rows of this chunk
    __shared__ float sT2[8][4][CHF];                 // 4 KB: per-wave T chunks
    int j = blockIdx.x / nbj;
    int b = blockIdx.x % nbj;
    int t = threadIdx.x;
    const float4* wsrc = (const float4*)(Wk + j * CHF * GOUT);
    for (int i2 = t; i2 < CHF * GOUT / 4; i2 += 512) ((float4*)sW)[i2] = wsrc[i2];
    int w = t >> 6, lane = t & 63, s = lane >> 4, u = lane & 15;
    int node = b * 32 + w * 4 + s;
    int beg = 0, deg = 0;
    if (node < n) { beg = offsets[node]; deg = offsets[node + 1] - beg; }
    int m = deg;
    m = max(m, __shfl_xor(m, 16));
    m = max(m, __shfl_xor(m, 32));
    const uint* inb_u = (const uint*)inb;
    size_t jbase = (size_t)j * n * 16;
    float tax = 0.f, tay = 0.f;
    for (int it = 0; it < m; it += 4) {
        uint q[4], uu[4];
#pragma unroll
        for (int k = 0; k < 4; ++k) {
            int idx = it + k;
            q[k] = (idx < deg) ? csr[beg + idx] : 0u;
        }
#pragma unroll
        for (int k = 0; k < 4; ++k)
            uu[k] = inb_u[jbase + (size_t)(q[k] >> 16) * 16 + u];
#pragma unroll
        for (int k = 0; k < 4; ++k) {
            float l = bflo(q[k]);
            tax += l * bflo(uu[k]);
            tay += l * bfhi(uu[k]);
        }
    }
    float ox = tax, oy = tay;
    if (node < n) {
        size_t base = jbase + (size_t)node * 16 + u;
        if (has_sub) {
            uint sv = ((const uint*)sub)[base];
            ox = 2.f * tax - bflo(sv);
            oy = 2.f * tay - bfhi(sv);
        }
        ((uint*)outb)[base] = (uint)f2bf(ox) | ((uint)f2bf(oy) << 16);
    }
    sT2[w][s][2 * u] = ox;
    sT2[w][s][2 * u + 1] = oy;
    __syncthreads();                      // covers sW staging; sT2 is wave-local
    // partial einsum: lane (s,u) -> out[node_s, u] and out[node_s, u+16]
    float a0 = 0.f, a1 = 0.f;
#pragma unroll
    for (int i = 0; i < CHF; ++i) {
        float tv = sT2[w][s][i];
        a0 += tv * sW[i * GOUT + u];
        a1 += tv * sW[i * GOUT + u + 16];
    }
    if (node < n) {
        atomicAdd(&out[(size_t)node * GOUT + u], a0);
        atomicAdd(&out[(size_t)node * GOUT + u + 16], a1);
    }
}

extern "C" void kernel_launch(void* const* d_in, const int* in_sizes, int n_in,
                              void* d_out, int out_size, void* d_ws, size_t ws_size,
                              hipStream_t stream) {
    const float* x = (const float*)d_in[0];
    const int* ei = (const int*)d_in[1];     // int32 per harness contract
    const float* ew = (const float*)d_in[2];
    const float* W = (const float*)d_in[3];
    const float* bias = (const float*)d_in[4];
    float* out = (float*)d_out;

    const int N = in_sizes[0] / FEAT;   // 50000
    const int E = in_sizes[1] / 2;      // 1600000
    const int NB = (N + SCB - 1) / SCB;
    const int NBUK = (N + 255) >> 8;    // 196
    // spmm node-blocks, padded to x8 so a block's XCD is stable across passes
    const int NBJ = (((N + 31) / 32 + 7) / 8) * 8;   // 1568

    char* p = (char*)d_ws;
    auto alloc = [&](size_t bytes) {
        char* q = p;
        p += (bytes + 255) & ~(size_t)255;
        return q;
    };
    int* cnt = (int*)alloc((size_t)N * 4);
    int* offsets = (int*)alloc(((size_t)N + 1) * 4);
    float* dinv = (float*)alloc((size_t)N * 4);
    int* partial = (int*)alloc((size_t)N * 4);
    int* blockSums = (int*)alloc((size_t)NB * 4);
    int* blockOffsets = (int*)alloc((size_t)NB * 4);
    int* bucketCursor = (int*)alloc((size_t)NBUK * 4);
    uint* csr = (uint*)alloc(((size_t)E + 64) * 4);  // +pad: predicated over-reads
    ushort* xb = (ushort*)alloc((size_t)N * FEAT * 2);
    ushort* Ab = (ushort*)alloc((size_t)N * FEAT * 2);
    ushort* Bb = (ushort*)alloc((size_t)N * FEAT * 2);
    uint2* staging = (uint2*)Ab;   // aliases Ab+Bb (dead before first spmm)
    (void)ws_size;

    hipMemsetAsync(bucketCursor, 0, (size_t)NBUK * 4, stream);

    bin_kernel<<<(E + CH - 1) / CH, 1024, 0, stream>>>(ei, ew, E, bucketCursor, staging);
    bucket_count_kernel<<<NBUK, 256, 0, stream>>>(staging, bucketCursor, cnt, N);
    scan1_kernel<<<NB, SCB, 0, stream>>>(cnt, partial, blockSums, dinv, N);
    scan2_kernel<<<1, SCB, 0, stream>>>(blockSums, blockOffsets, NB, offsets + N);
    scan3_kernel<<<NB, SCB, 0, stream>>>(partial, blockOffsets, offsets, N);
    scatter_kernel<<<NBUK, 256, 0, stream>>>(staging, bucketCursor, offsets, dinv, csr, N);

    // out = bias + x*W0 ; xb = chunked bf16(x)
    cvt_einsum0_kernel<<<(N + 7) / 8, 256, 0, stream>>>(x, xb, W, bias, out, N);

    dim3 sg(NCH * NBJ);
    // Tx1 = S(x);            out += Tx1*W1
    spmm_chunk_kernel<<<sg, 512, 0, stream>>>(xb, nullptr, Ab, offsets, csr,
                                              W + 1 * FEAT * GOUT, out, N, 0, NBJ);
    // Tx2 = 2*S(Tx1) - x;    out += Tx2*W2
    spmm_chunk_kernel<<<sg, 512, 0, stream>>>(Ab, xb, Bb, offsets, csr,
                                              W + 2 * FEAT * GOUT, out, N, 1, NBJ);
    // Tx3 = 2*S(Tx2) - Tx1;  out += Tx3*W3   (outb aliases sub; read-before-write)
    spmm_chunk_kernel<<<sg, 512, 0, stream>>>(Bb, Ab, Ab, offsets, csr,
                                              W + 3 * FEAT * GOUT, out, N, 1, NBJ);
}

// Round 9
// 357.767 us; speedup vs baseline: 1.5316x; 1.0737x over previous
//
#include <hip/hip_runtime.h>

// ChebTimeConv: N=50000, E=1.6M, H=4, F_IN=F_OUT=32, K=4, Q=1.
// CSR build: binned counting sort (bin -> bucket_count -> scan -> scatter).
// SpMM: feature-chunked passes ([chunk][node][32f] bf16 mirrors; per-pass
// working set 3.2 MB < 4 MiB/XCD L2 -> FETCH at compulsory floor).
// This round: gather shape 8 lanes/edge x uint2 (4 feats/lane), unroll 8
// -> half the vmem/addr instructions, 4x in-flight lines per wave.
// CSR entry: (col<<16)|bf16(lap). edge_index arrives int32.

#define FEAT 128   // H * F_IN
#define GOUT 32    // F_OUT
#define NCH 4      // feature chunks
#define CHF 32     // feats per chunk
#define SCB 256
#define CH 4096    // edges per bin block
#define WCAP 16384 // scatter LDS window entries
#define CAP 12032  // staging slots per bucket
#define TROW 160   // padded LDS row for cvt kernel
#define UNR 8      // spmm gather unroll

typedef unsigned int uint;
typedef unsigned short ushort;

__device__ __forceinline__ ushort f2bf(float f) {
    uint u = __float_as_uint(f);
    return (ushort)((u + 0x7fffu + ((u >> 16) & 1u)) >> 16);   // RNE
}
__device__ __forceinline__ float bflo(uint u) { return __uint_as_float(u << 16); }
__device__ __forceinline__ float bfhi(uint u) { return __uint_as_float(u & 0xffff0000u); }
__device__ __forceinline__ int tidx(int i) { return i + ((i >> 4) << 2); }

// ---- phase 1: bin edges into per-(block,bucket) staging runs ----
__global__ __launch_bounds__(1024) void bin_kernel(
    const int* __restrict__ ei, const float* __restrict__ ew, int E,
    int* __restrict__ bucketCursor, uint2* __restrict__ staging) {
    __shared__ int hist[256];
    __shared__ int base[256];
    int e0 = blockIdx.x * CH;
    int e1 = min(e0 + CH, E);
    int t = threadIdx.x;
    if (t < 256) hist[t] = 0;
    __syncthreads();
    for (int e = e0 + t; e < e1; e += 1024) {
        int r = ei[e], c = ei[(size_t)E + e];
        if (r != c) atomicAdd(&hist[r >> 8], 1);
    }
    __syncthreads();
    if (t < 256) {
        int h = hist[t];
        if (h > 0) {
            int run = atomicAdd(&bucketCursor[t], h);
            base[t] = t * CAP + run;
        }
        hist[t] = 0;
    }
    __syncthreads();
    for (int e = e0 + t; e < e1; e += 1024) {
        int r = ei[e], c = ei[(size_t)E + e];
        if (r == c) continue;
        float w = ew[e];
        int bk = r >> 8;
        int j = atomicAdd(&hist[bk], 1);
        int idx = base[bk] + j;
        if (idx < (bk + 1) * CAP)   // impossible-overflow guard
            staging[idx] = make_uint2(__float_as_uint(w), ((uint)c << 16) | (uint)(r & 255));
    }
}

// ---- per-row counts from staging (contiguous reads, LDS hist) ----
__global__ __launch_bounds__(256) void bucket_count_kernel(
    const uint2* __restrict__ staging, const int* __restrict__ bucketCursor,
    int* __restrict__ cnt, int n) {
    __shared__ int hist[256];
    int b = blockIdx.x;
    int t = threadIdx.x;
    hist[t] = 0;
    __syncthreads();
    int nrec = bucketCursor[b];
    const uint2* src = staging + (size_t)b * CAP;
    for (int k = t; k < nrec; k += 256)
        atomicAdd(&hist[src[k].y & 255], 1);
    __syncthreads();
    int r = (b << 8) + t;
    if (r < n) cnt[r] = hist[t];
}

// ---- two-level scan (dinv folded into scan1) ----
__global__ void scan1_kernel(const int* __restrict__ cnt, int* __restrict__ partial,
                             int* __restrict__ blockSums, float* __restrict__ dinv, int n) {
    __shared__ int buf[2][SCB];
    int t = threadIdx.x;
    int i = blockIdx.x * SCB + t;
    int v = (i < n) ? cnt[i] : 0;
    if (i < n) dinv[i] = (v > 0) ? rsqrtf((float)v) : 0.0f;
    buf[0][t] = v;
    __syncthreads();
    int src = 0;
    for (int off = 1; off < SCB; off <<= 1) {
        int d = src ^ 1;
        buf[d][t] = buf[src][t] + ((t >= off) ? buf[src][t - off] : 0);
        __syncthreads();
        src = d;
    }
    int incl = buf[src][t];
    if (i < n) partial[i] = incl - v;
    if (t == SCB - 1) blockSums[blockIdx.x] = incl;
}

__global__ void scan2_kernel(const int* __restrict__ blockSums, int* __restrict__ blockOffsets,
                             int nb, int* __restrict__ total_out) {
    __shared__ int buf[2][SCB];
    __shared__ int carry_s;
    if (threadIdx.x == 0) carry_s = 0;
    __syncthreads();
    for (int base = 0; base < nb; base += SCB) {
        int i = base + (int)threadIdx.x;
        int v = (i < nb) ? blockSums[i] : 0;
        buf[0][threadIdx.x] = v;
        __syncthreads();
        int src = 0;
        for (int off = 1; off < SCB; off <<= 1) {
            int d = src ^ 1;
            buf[d][threadIdx.x] = buf[src][threadIdx.x] +
                                  ((threadIdx.x >= (unsigned)off) ? buf[src][threadIdx.x - off] : 0);
            __syncthreads();
            src = d;
        }
        int incl = buf[src][threadIdx.x];
        int c = carry_s;
        if (i < nb) blockOffsets[i] = c + incl - v;
        __syncthreads();
        if (threadIdx.x == SCB - 1) carry_s = c + incl;
        __syncthreads();
    }
    if (threadIdx.x == 0) *total_out = carry_s;
}

__global__ void scan3_kernel(const int* __restrict__ partial, const int* __restrict__ blockOffsets,
                             int* __restrict__ offsets, int n) {
    int i = blockIdx.x * blockDim.x + threadIdx.x;
    if (i < n) offsets[i] = partial[i] + blockOffsets[i / SCB];
}

// ---- phase 2: per-bucket scatter via LDS window -> coalesced csr write ----
__global__ __launch_bounds__(256) void scatter_kernel(
    const uint2* __restrict__ staging, const int* __restrict__ bucketCursor,
    const int* __restrict__ offsets, const float* __restrict__ dinv,
    uint* __restrict__ csr, int n) {
    __shared__ uint win[WCAP];          // 64 KB
    __shared__ int roff[256];
    __shared__ int rcur[256];
    __shared__ float dloc[256];
    int b = blockIdx.x;
    int r0 = b << 8;
    int nrows = min(256, n - r0);
    int t = threadIdx.x;
    if (t < nrows) {
        roff[t] = offsets[r0 + t];
        dloc[t] = dinv[r0 + t];
    }
    rcur[t] = 0;
    __syncthreads();
    int wbeg = roff[0];
    int nrec = bucketCursor[b];
    bool fit = (nrec <= WCAP);
    const uint2* src = staging + (size_t)b * CAP;
    for (int k = t; k < nrec; k += 256) {
        uint2 rec = src[k];
        int col = rec.y >> 16;
        int rl = rec.y & 255;
        float lap = -dloc[rl] * __uint_as_float(rec.x) * dinv[col];
        uint colap = ((uint)col << 16) | (uint)f2bf(lap);
        int pos = roff[rl] + atomicAdd(&rcur[rl], 1);
        if (fit) win[pos - wbeg] = colap;
        else csr[pos] = colap;
    }
    __syncthreads();
    if (fit)
        for (int k = t; k < nrec; k += 256) csr[wbeg + k] = win[k];
}

// ---- fused: x -> CHUNKED bf16 mirror, plus out = bias + x*W0 ----
__global__ __launch_bounds__(256) void cvt_einsum0_kernel(
    const float* __restrict__ x, ushort* __restrict__ xb,
    const float* __restrict__ W0, const float* __restrict__ bias,
    float* __restrict__ out, int n) {
    __shared__ __align__(16) float4 sW4[FEAT * GOUT / 4];
    __shared__ __align__(16) float sT[8 * TROW];
    const float* sW = (const float*)sW4;
    int t = threadIdx.x;
    const float4* wsrc = (const float4*)W0;
    for (int idx = t; idx < FEAT * GOUT / 4; idx += 256) sW4[idx] = wsrc[idx];
    int node = blockIdx.x * 8 + (t >> 5);
    int f0 = 4 * (t & 31);
    float4 v = make_float4(0.f, 0.f, 0.f, 0.f);
    if (node < n) {
        v = *(const float4*)(x + (size_t)node * FEAT + f0);
        ushort4 o;
        o.x = f2bf(v.x); o.y = f2bf(v.y); o.z = f2bf(v.z); o.w = f2bf(v.w);
        int j0 = f0 >> 5;                 // chunk of these 4 feats
        *(ushort4*)(xb + ((size_t)j0 * n + node) * CHF + (f0 & 31)) = o;
    }
    int nl = t >> 5;
    *(float4*)&sT[nl * TROW + tidx(f0)] = v;
    __syncthreads();
    int l32 = t & 31;
    int q = l32 & 7;
    int part = l32 >> 3;
    float4 a4 = make_float4(0.f, 0.f, 0.f, 0.f);
#pragma unroll
    for (int j = 0; j < 8; ++j) {
        float4 t4 = *(const float4*)&sT[nl * TROW + tidx(part * 32 + 4 * j)];
        const float* wv0 = &sW[(part * 32 + 4 * j) * GOUT + 4 * q];
        float4 w0 = *(const float4*)(wv0);
        float4 w1 = *(const float4*)(wv0 + GOUT);
        float4 w2 = *(const float4*)(wv0 + 2 * GOUT);
        float4 w3 = *(const float4*)(wv0 + 3 * GOUT);
        a4.x += t4.x * w0.x + t4.y * w1.x + t4.z * w2.x + t4.w * w3.x;
        a4.y += t4.x * w0.y + t4.y * w1.y + t4.z * w2.y + t4.w * w3.y;
        a4.z += t4.x * w0.z + t4.y * w1.z + t4.z * w2.z + t4.w * w3.z;
        a4.w += t4.x * w0.w + t4.y * w1.w + t4.z * w2.w + t4.w * w3.w;
    }
    a4.x += __shfl_down(a4.x, 8);  a4.y += __shfl_down(a4.y, 8);
    a4.z += __shfl_down(a4.z, 8);  a4.w += __shfl_down(a4.w, 8);
    a4.x += __shfl_down(a4.x, 16); a4.y += __shfl_down(a4.y, 16);
    a4.z += __shfl_down(a4.z, 16); a4.w += __shfl_down(a4.w, 16);
    if (part == 0 && node < n) {
        const float4 b4 = *(const float4*)(bias + 4 * q);
        float4 r;
        r.x = a4.x + b4.x; r.y = a4.y + b4.y; r.z = a4.z + b4.z; r.w = a4.w + b4.w;
        *(float4*)(out + (size_t)node * GOUT + 4 * q) = r;
    }
}

// ---- chunked SpMM pass + partial einsum ----
// grid = NCH * nbj (j-major). Wave = 8 nodes x 8 lanes; lane = uint2 (4 feats).
__global__ __launch_bounds__(512) void spmm_chunk_kernel(
    const ushort* __restrict__ inb, const ushort* __restrict__ sub,
    ushort* __restrict__ outb, const int* __restrict__ offsets,
    const uint* __restrict__ csr, const float* __restrict__ Wk,
    float* __restrict__ out, int n, int has_sub, int nbj) {
    __shared__ __align__(16) float sW[CHF * GOUT];   // 4 KB: W rows of this chunk
    __shared__ float sT2[8][8][CHF + 1];             // 8.25 KB, +1 pad (banks)
    int j = blockIdx.x / nbj;
    int b = blockIdx.x % nbj;
    int t = threadIdx.x;
    const float4* wsrc = (const float4*)(Wk + j * CHF * GOUT);
    for (int i2 = t; i2 < CHF * GOUT / 4; i2 += 512) ((float4*)sW)[i2] = wsrc[i2];
    int w = t >> 6, lane = t & 63, s = lane >> 3, u = lane & 7;
    int node = b * 64 + w * 8 + s;
    int beg = 0, deg = 0;
    if (node < n) { beg = offsets[node]; deg = offsets[node + 1] - beg; }
    int m = deg;
    m = max(m, __shfl_xor(m, 8));
    m = max(m, __shfl_xor(m, 16));
    m = max(m, __shfl_xor(m, 32));
    const uint2* inb_u2 = (const uint2*)inb;
    size_t jb2 = (size_t)j * n * 8;                  // chunk base, uint2 units
    size_t obase = jb2 + (size_t)node * 8 + u;
    uint2 sv = make_uint2(0u, 0u);
    if (has_sub && node < n) sv = ((const uint2*)sub)[obase];   // early, independent
    float a0 = 0.f, a1 = 0.f, a2 = 0.f, a3 = 0.f;
    for (int it = 0; it < m; it += UNR) {
        uint q[UNR];
        uint2 uu[UNR];
#pragma unroll
        for (int k = 0; k < UNR; ++k) {
            int idx = it + k;
            q[k] = (idx < deg) ? csr[beg + idx] : 0u;
        }
#pragma unroll
        for (int k = 0; k < UNR; ++k)
            uu[k] = inb_u2[jb2 + (size_t)(q[k] >> 16) * 8 + u];
#pragma unroll
        for (int k = 0; k < UNR; ++k) {
            float l = bflo(q[k]);
            a0 += l * bflo(uu[k].x);
            a1 += l * bfhi(uu[k].x);
            a2 += l * bflo(uu[k].y);
            a3 += l * bfhi(uu[k].y);
        }
    }
    if (has_sub) {
        a0 = 2.f * a0 - bflo(sv.x);
        a1 = 2.f * a1 - bfhi(sv.x);
        a2 = 2.f * a2 - bflo(sv.y);
        a3 = 2.f * a3 - bfhi(sv.y);
    }
    if (node < n) {
        uint2 o;
        o.x = (uint)f2bf(a0) | ((uint)f2bf(a1) << 16);
        o.y = (uint)f2bf(a2) | ((uint)f2bf(a3) << 16);
        ((uint2*)outb)[obase] = o;
    }
    sT2[w][s][4 * u + 0] = a0;
    sT2[w][s][4 * u + 1] = a1;
    sT2[w][s][4 * u + 2] = a2;
    sT2[w][s][4 * u + 3] = a3;
    __syncthreads();                      // covers sW staging; sT2 is wave-local
    // partial einsum: lane (s,u) -> out[node_s, u + 8k], k=0..3
    float e0 = 0.f, e1 = 0.f, e2 = 0.f, e3 = 0.f;
#pragma unroll
    for (int i = 0; i < CHF; ++i) {
        float tv = sT2[w][s][i];          // broadcast across u
        e0 += tv * sW[i * GOUT + u];
        e1 += tv * sW[i * GOUT + u + 8];
        e2 += tv * sW[i * GOUT + u + 16];
        e3 += tv * sW[i * GOUT + u + 24];
    }
    if (node < n) {
        float* po = out + (size_t)node * GOUT;
        atomicAdd(po + u, e0);
        atomicAdd(po + u + 8, e1);
        atomicAdd(po + u + 16, e2);
        atomicAdd(po + u + 24, e3);
    }
}

extern "C" void kernel_launch(void* const* d_in, const int* in_sizes, int n_in,
                              void* d_out, int out_size, void* d_ws, size_t ws_size,
                              hipStream_t stream) {
    const float* x = (const float*)d_in[0];
    const int* ei = (const int*)d_in[1];     // int32 per harness contract
    const float* ew = (const float*)d_in[2];
    const float* W = (const float*)d_in[3];
    const float* bias = (const float*)d_in[4];
    float* out = (float*)d_out;

    const int N = in_sizes[0] / FEAT;   // 50000
    const int E = in_sizes[1] / 2;      // 1600000
    const int NB = (N + SCB - 1) / SCB;
    const int NBUK = (N + 255) >> 8;    // 196
    // spmm node-blocks (64 nodes/block), padded to x8 for stable XCD mapping
    const int NBJ = (((N + 63) / 64 + 7) / 8) * 8;   // 784

    char* p = (char*)d_ws;
    auto alloc = [&](size_t bytes) {
        char* q = p;
        p += (bytes + 255) & ~(size_t)255;
        return q;
    };
    int* cnt = (int*)alloc((size_t)N * 4);
    int* offsets = (int*)alloc(((size_t)N + 1) * 4);
    float* dinv = (float*)alloc((size_t)N * 4);
    int* partial = (int*)alloc((size_t)N * 4);
    int* blockSums = (int*)alloc((size_t)NB * 4);
    int* blockOffsets = (int*)alloc((size_t)NB * 4);
    int* bucketCursor = (int*)alloc((size_t)NBUK * 4);
    uint* csr = (uint*)alloc(((size_t)E + 64) * 4);  // +pad: predicated over-reads
    ushort* xb = (ushort*)alloc((size_t)N * FEAT * 2);
    ushort* Ab = (ushort*)alloc((size_t)N * FEAT * 2);
    ushort* Bb = (ushort*)alloc((size_t)N * FEAT * 2);
    uint2* staging = (uint2*)Ab;   // aliases Ab+Bb (dead before first spmm)
    (void)ws_size;

    hipMemsetAsync(bucketCursor, 0, (size_t)NBUK * 4, stream);

    bin_kernel<<<(E + CH - 1) / CH, 1024, 0, stream>>>(ei, ew, E, bucketCursor, staging);
    bucket_count_kernel<<<NBUK, 256, 0, stream>>>(staging, bucketCursor, cnt, N);
    scan1_kernel<<<NB, SCB, 0, stream>>>(cnt, partial, blockSums, dinv, N);
    scan2_kernel<<<1, SCB, 0, stream>>>(blockSums, blockOffsets, NB, offsets + N);
    scan3_kernel<<<NB, SCB, 0, stream>>>(partial, blockOffsets, offsets, N);
    scatter_kernel<<<NBUK, 256, 0, stream>>>(staging, bucketCursor, offsets, dinv, csr, N);

    // out = bias + x*W0 ; xb = chunked bf16(x)
    cvt_einsum0_kernel<<<(N + 7) / 8, 256, 0, stream>>>(x, xb, W, bias, out, N);

    dim3 sg(NCH * NBJ);
    // Tx1 = S(x);            out += Tx1*W1
    spmm_chunk_kernel<<<sg, 512, 0, stream>>>(xb, nullptr, Ab, offsets, csr,
                                              W + 1 * FEAT * GOUT, out, N, 0, NBJ);
    // Tx2 = 2*S(Tx1) - x;    out += Tx2*W2
    spmm_chunk_kernel<<<sg, 512, 0, stream>>>(Ab, xb, Bb, offsets, csr,
                                              W + 2 * FEAT * GOUT, out, N, 1, NBJ);
    // Tx3 = 2*S(Tx2) - Tx1;  out += Tx3*W3   (outb aliases sub; read-before-write)
    spmm_chunk_kernel<<<sg, 512, 0, stream>>>(Bb, Ab, Ab, offsets, csr,
                                              W + 3 * FEAT * GOUT, out, N, 1, NBJ);
}